// Round 14
// baseline (243.011 us; speedup 1.0000x reference)
//
#include <hip/hip_runtime.h>
#include <hip/hip_bf16.h>
#include <math.h>

#define HWq 10000
#define Cq 256   // in channels (K)
#define Oq 256   // out channels (M)

typedef __attribute__((ext_vector_type(8))) short short8v;           // 8 bf16
typedef __attribute__((ext_vector_type(4))) float f32x4;

__device__ __forceinline__ short f2bf(float f) {
    __hip_bfloat16 h = __float2bfloat16(f);      // RNE; pairs fuse to v_cvt_pk_bf16_f32
    return *reinterpret_cast<short*>(&h);
}
__device__ __forceinline__ float bf2f(unsigned short u) {
    return __uint_as_float((unsigned)u << 16);
}

// XOR swizzle of 16B units within a 64B k-row
__device__ __forceinline__ int swz(int row, int g) {
    return g ^ (row & 3) ^ ((row >> 2) & 1);
}

// ---------------------------------------------------------------------------
// Kernel 1: 1x1 conv as bf16 MFMA GEMM, y stored as bf16.
// Block tile 64o x 128p (acc 2x4 = 32 regs -> ~5 waves/SIMD vs 3 at 128x128),
// BK=32, 4 waves (2x2, wave tile 32x64), single LDS buffer, reg-prefetch.
// Accumulates per-batch sum/sumsq (f32) into stats[0..7] / stats[8..15].
// ---------------------------------------------------------------------------
__global__ __launch_bounds__(256) void conv_mfma(const float* __restrict__ feat,
                                                 const float* __restrict__ convw,
                                                 unsigned short* __restrict__ y,
                                                 float* __restrict__ stats) {
    __shared__ __align__(16) short Albuf[64 * 32];    // [o][k] bf16, swizzled
    __shared__ __align__(16) short Blbuf[128 * 32];   // [p][k] bf16, swizzled
    __shared__ float redbuf[8];

    const int b  = blockIdx.z;
    const int o0 = blockIdx.y * 64;
    const int p0 = blockIdx.x * 128;
    const int t  = threadIdx.x;
    const int w  = t >> 6;
    const int l  = t & 63;
    const int wo = (w >> 1) * 32;   // wave o-offset (0 / 32)
    const int wp = (w & 1) * 64;    // wave p-offset (0 / 64)

    const float* fb = feat + (size_t)b * Cq * HWq;

    f32x4 acc[2][4];
    #pragma unroll
    for (int i = 0; i < 2; ++i)
        #pragma unroll
        for (int j = 0; j < 4; ++j)
            acc[i][j] = (f32x4){0.f, 0.f, 0.f, 0.f};

    const int oA  = t >> 2;         // 0..63
    const int kuA = t & 3;          // 16B k-unit
    const float* aptr = convw + (size_t)(o0 + oA) * Cq + kuA * 8;

    int pgB[2];
    #pragma unroll
    for (int pass = 0; pass < 2; ++pass) {
        int pg = p0 + pass * 64 + l;
        pgB[pass] = (pg > HWq - 1) ? (HWq - 1) : pg;
    }

    const int fr_g = l >> 4;
    const int fr_r = l & 15;

    float4 ra0, ra1;
    float  rb[2][8];

    auto LOADG = [&](int k0) {
        ra0 = *(const float4*)(aptr + k0);
        ra1 = *(const float4*)(aptr + k0 + 4);
        #pragma unroll
        for (int pass = 0; pass < 2; ++pass) {
            const float* fk = fb + (size_t)(k0 + w * 8) * HWq + pgB[pass];
            #pragma unroll
            for (int jj = 0; jj < 8; ++jj)
                rb[pass][jj] = fk[(size_t)jj * HWq];
        }
    };

    LOADG(0);

    for (int k0 = 0; k0 < Cq; k0 += 32) {
        if (k0) __syncthreads();               // LDS reads of prev step done

        // ---- LDS write from regs (f32 -> bf16)
        {
            short8v s;
            s[0]=f2bf(ra0.x); s[1]=f2bf(ra0.y); s[2]=f2bf(ra0.z); s[3]=f2bf(ra0.w);
            s[4]=f2bf(ra1.x); s[5]=f2bf(ra1.y); s[6]=f2bf(ra1.z); s[7]=f2bf(ra1.w);
            *(short8v*)((char*)Albuf + oA * 64 + swz(oA, kuA) * 16) = s;
            #pragma unroll
            for (int pass = 0; pass < 2; ++pass) {
                short8v sb;
                #pragma unroll
                for (int jj = 0; jj < 8; ++jj) sb[jj] = f2bf(rb[pass][jj]);
                int p = pass * 64 + l;
                *(short8v*)((char*)Blbuf + p * 64 + swz(p, w) * 16) = sb;
            }
        }
        __syncthreads();

        if (k0 < Cq - 32) LOADG(k0 + 32);      // prefetch next chunk (hides under MFMA)

        short8v af[2], bfv[4];
        #pragma unroll
        for (int i = 0; i < 2; ++i) {
            int row = wo + i * 16 + fr_r;
            af[i] = *(const short8v*)((const char*)Albuf + row * 64 + swz(row, fr_g) * 16);
        }
        #pragma unroll
        for (int j = 0; j < 4; ++j) {
            int row = wp + j * 16 + fr_r;
            bfv[j] = *(const short8v*)((const char*)Blbuf + row * 64 + swz(row, fr_g) * 16);
        }
        #pragma unroll
        for (int i = 0; i < 2; ++i)
            #pragma unroll
            for (int j = 0; j < 4; ++j)
                acc[i][j] = __builtin_amdgcn_mfma_f32_16x16x32_bf16(af[i], bfv[j], acc[i][j], 0, 0, 0);
    }

    // ---- epilogue: bf16 y store + f32 stats
    float lsum = 0.f, lsq = 0.f;
    #pragma unroll
    for (int i = 0; i < 2; ++i) {
        const int obase = o0 + wo + i * 16 + (l >> 4) * 4;
        #pragma unroll
        for (int j = 0; j < 4; ++j) {
            const int p = p0 + wp + j * 16 + (l & 15);
            if (p < HWq) {
                #pragma unroll
                for (int r = 0; r < 4; ++r) {
                    float v = acc[i][j][r];
                    y[((size_t)(b * Oq + obase + r)) * HWq + p] = (unsigned short)f2bf(v);
                    lsum += v;
                    lsq  += v * v;
                }
            }
        }
    }
    #pragma unroll
    for (int m = 1; m < 64; m <<= 1) {
        lsum += __shfl_xor(lsum, m);
        lsq  += __shfl_xor(lsq, m);
    }
    if (l == 0) { redbuf[w] = lsum; redbuf[4 + w] = lsq; }
    __syncthreads();
    if (t == 0) {
        atomicAdd(&stats[b],     redbuf[0] + redbuf[1] + redbuf[2] + redbuf[3]);
        atomicAdd(&stats[8 + b], redbuf[4] + redbuf[5] + redbuf[6] + redbuf[7]);
    }
}

// ---------------------------------------------------------------------------
// Kernel 2: per-(b,c) plane, 8 waves (512 threads). Each wave owns rows
// wave+8i. Row prefix along x in LDS; pooling = per-box row-range sums,
// 8 lanes/box. (R13 version, unchanged.)
// ---------------------------------------------------------------------------
__global__ __launch_bounds__(512) void integral_pool(const unsigned short* __restrict__ y,
                                                     const float* __restrict__ boxes,
                                                     const float* __restrict__ stats,
                                                     const float* __restrict__ gnw,
                                                     const float* __restrict__ gnb,
                                                     float* __restrict__ pooled) {
    __shared__ float Sl[10000];          // row-prefix values

    const int plane = blockIdx.x;        // b*256 + c
    const int b = plane >> 8;
    const int c = plane & 255;
    const int wave = threadIdx.x >> 6;   // 0..7
    const int lane = threadIdx.x & 63;

    const float invM = 1.f / 2560000.f;
    const float mu   = stats[b] * invM;
    const float msq  = stats[8 + b] * invM;
    const float rs   = rsqrtf(msq - mu * mu + 1e-5f);
    const float scale = gnw[c] * rs;
    const float shift = gnb[c] - mu * scale;

    const unsigned short* yp = y + (size_t)plane * HWq;

    // row prefix: wave owns rows wave+8i; 2-row ILP unroll (7 iterations).
    for (int i = 0; i < 13; i += 2) {
        const int r0 = wave + 8 * i;
        const int r1 = r0 + 8;
        const bool has0 = r0 < 100;
        const bool has1 = r1 < 100;
        float a0 = 0.f, b0 = 0.f, a1 = 0.f, b1 = 0.f;
        if (lane < 50) {
            if (has0) {
                ushort2 u0 = *(const ushort2*)(yp + r0 * 100 + 2 * lane);
                float v0 = bf2f(u0.x) * scale + shift;
                float v1 = bf2f(u0.y) * scale + shift;
                a0 = v0 / (1.f + __expf(-v0));
                b0 = v1 / (1.f + __expf(-v1));
            }
            if (has1) {
                ushort2 u1 = *(const ushort2*)(yp + r1 * 100 + 2 * lane);
                float w0 = bf2f(u1.x) * scale + shift;
                float w1 = bf2f(u1.y) * scale + shift;
                a1 = w0 / (1.f + __expf(-w0));
                b1 = w1 / (1.f + __expf(-w1));
            }
        }
        float p0 = a0 + b0;
        float p1 = a1 + b1;
        #pragma unroll
        for (int m = 1; m < 64; m <<= 1) {
            float t0 = __shfl_up(p0, m);
            float t1 = __shfl_up(p1, m);
            if (lane >= m) { p0 += t0; p1 += t1; }
        }
        if (lane < 50) {
            if (has0) {
                float2 o0 = {p0 - b0, p0};            // inclusive prefix at x=2l, 2l+1
                *(float2*)(&Sl[r0 * 100 + 2 * lane]) = o0;
            }
            if (has1) {
                float2 o1 = {p1 - b1, p1};
                *(float2*)(&Sl[r1 * 100 + 2 * lane]) = o1;
            }
        }
    }
    __syncthreads();

    // pooling: 8 lanes per box; lane j sums rows iy1+j, step 8
    {
        const int grp = lane >> 3;           // 0..7
        const int j   = lane & 7;
        const int n   = wave * 8 + grp;      // 0..63
        const float4 bx = *(const float4*)(boxes + ((size_t)b * 64 + n) * 4);

        float x1f = fminf(bx.x, bx.z) * 100.f;
        float x2f = fmaxf(bx.x, bx.z) * 100.f;
        float y1f = fminf(bx.y, bx.w) * 100.f;
        float y2f = fmaxf(bx.y, bx.w) * 100.f;
        x1f = fminf(fmaxf(floorf(fminf(fmaxf(x1f, 0.f), 100.f)), 0.f), 100.f);
        x2f = fminf(fmaxf(ceilf (fminf(fmaxf(x2f, 0.f), 100.f)), 0.f), 100.f);
        y1f = fminf(fmaxf(floorf(fminf(fmaxf(y1f, 0.f), 100.f)), 0.f), 100.f);
        y2f = fminf(fmaxf(ceilf (fminf(fmaxf(y2f, 0.f), 100.f)), 0.f), 100.f);
        const int ix1 = (int)x1f, ix2 = (int)x2f;
        const int iy1 = (int)y1f, iy2 = (int)y2f;
        const int cnt = (ix2 - ix1) * (iy2 - iy1);

        float v = 0.f;
        if (cnt > 0) {
            const int colR = ix2 - 1;
            const int colL = ix1 - 1;
            for (int h = iy1 + j; h < iy2; h += 8) {
                float s = Sl[h * 100 + colR];
                if (colL >= 0) s -= Sl[h * 100 + colL];
                v += s;
            }
        }
        v += __shfl_xor(v, 1);
        v += __shfl_xor(v, 2);
        v += __shfl_xor(v, 4);
        if (j == 0)
            pooled[((size_t)b * 64 + n) * Cq + c] = (cnt > 0) ? v / (float)cnt : 0.f;
    }
}

// ---------------------------------------------------------------------------
// Kernel 3: MLP (256->128 SiLU ->64) + L2 normalize. One block per (b,n).
// 4-way ILP accumulators break the dependent-FMA chain. (R12 version.)
// ---------------------------------------------------------------------------
__global__ __launch_bounds__(128) void mlp_kernel(const float* __restrict__ pooled,
                                                  const float* __restrict__ w1,
                                                  const float* __restrict__ b1,
                                                  const float* __restrict__ w2,
                                                  const float* __restrict__ b2,
                                                  float* __restrict__ emb,
                                                  float* __restrict__ raw) {
    __shared__ float ps[256];
    __shared__ float hs[128];
    const int bn = blockIdx.x;
    const int t  = threadIdx.x;

    ps[t]       = pooled[(size_t)bn * 256 + t];
    ps[t + 128] = pooled[(size_t)bn * 256 + t + 128];
    __syncthreads();

    float a0 = 0.f, a1 = 0.f, a2 = 0.f, a3 = 0.f;
    #pragma unroll 4
    for (int c = 0; c < 256; c += 4) {
        a0 += ps[c]     * w1[c * 128 + t];
        a1 += ps[c + 1] * w1[(c + 1) * 128 + t];
        a2 += ps[c + 2] * w1[(c + 2) * 128 + t];
        a3 += ps[c + 3] * w1[(c + 3) * 128 + t];
    }
    float a = b1[t] + ((a0 + a1) + (a2 + a3));
    hs[t] = a / (1.f + __expf(-a));
    __syncthreads();

    if (t < 64) {
        float r0 = 0.f, r1 = 0.f, r2 = 0.f, r3 = 0.f;
        #pragma unroll 4
        for (int h = 0; h < 128; h += 4) {
            r0 += hs[h]     * w2[h * 64 + t];
            r1 += hs[h + 1] * w2[(h + 1) * 64 + t];
            r2 += hs[h + 2] * w2[(h + 2) * 64 + t];
            r3 += hs[h + 3] * w2[(h + 3) * 64 + t];
        }
        float r = b2[t] + ((r0 + r1) + (r2 + r3));
        raw[(size_t)bn * 64 + t] = r;
        float s = r * r;
        #pragma unroll
        for (int m = 1; m < 64; m <<= 1) s += __shfl_xor(s, m);
        float nrm = fmaxf(sqrtf(s), 1e-6f);
        emb[(size_t)bn * 64 + t] = r / nrm;
    }
}

// ---------------------------------------------------------------------------
extern "C" void kernel_launch(void* const* d_in, const int* in_sizes, int n_in,
                              void* d_out, int out_size, void* d_ws, size_t ws_size,
                              hipStream_t stream) {
    const float* feat  = (const float*)d_in[0];
    const float* boxes = (const float*)d_in[1];
    const float* convw = (const float*)d_in[2];
    const float* gnw   = (const float*)d_in[3];
    const float* gnb   = (const float*)d_in[4];
    const float* w1    = (const float*)d_in[5];
    const float* b1    = (const float*)d_in[6];
    const float* w2    = (const float*)d_in[7];
    const float* b2    = (const float*)d_in[8];

    float* out    = (float*)d_out;
    float* emb    = out;             // [8,64,64]   = 32768
    float* raw    = out + 32768;     // [8,64,64]   = 32768
    float* pooled = out + 65536;     // [8,64,256]  = 131072

    unsigned short* y = (unsigned short*)d_ws;                     // 8*256*10000 bf16
    float* stats = (float*)((char*)d_ws + (size_t)8 * 256 * 10000 * 2);

    hipMemsetAsync(stats, 0, 16 * sizeof(float), stream);

    dim3 g1((HWq + 127) / 128, 4, 8);   // 79 x 4 x 8 = 2528 blocks
    conv_mfma<<<g1, 256, 0, stream>>>(feat, convw, y, stats);

    integral_pool<<<2048, 512, 0, stream>>>(y, boxes, stats, gnw, gnb, pooled);

    mlp_kernel<<<512, 128, 0, stream>>>(pooled, w1, b1, w2, b2, emb, raw);
}

// Round 15
// 212.682 us; speedup vs baseline: 1.1426x; 1.1426x over previous
//
#include <hip/hip_runtime.h>
#include <hip/hip_bf16.h>
#include <math.h>

#define HWq 10000
#define Cq 256   // in channels (K)
#define Oq 256   // out channels (M)

typedef __attribute__((ext_vector_type(8))) short short8v;           // 8 bf16
typedef __attribute__((ext_vector_type(4))) float f32x4;

__device__ __forceinline__ short f2bf(float f) {
    __hip_bfloat16 h = __float2bfloat16(f);      // RNE; pairs fuse to v_cvt_pk_bf16_f32
    return *reinterpret_cast<short*>(&h);
}
__device__ __forceinline__ float bf2f(unsigned short u) {
    return __uint_as_float((unsigned)u << 16);
}

// XOR swizzle of 16B units within a 64B k-row
__device__ __forceinline__ int swz(int row, int g) {
    return g ^ (row & 3) ^ ((row >> 2) & 1);
}

// ---------------------------------------------------------------------------
// Kernel 1: 1x1 conv as bf16 MFMA GEMM, y stored as bf16.
// Block tile 128o x 128p (87 MB fetch — 64-o tile doubled HBM, R14 regression),
// BK=32, EIGHT waves (4o x 2p, wave tile 32x64, acc 2x4 = 32 regs) for
// occupancy: more, smaller waves to cover HBM load latency. Single LDS buffer.
// Accumulates per-batch sum/sumsq (f32) into stats[0..7] / stats[8..15].
// ---------------------------------------------------------------------------
__global__ __launch_bounds__(512) void conv_mfma(const float* __restrict__ feat,
                                                 const float* __restrict__ convw,
                                                 unsigned short* __restrict__ y,
                                                 float* __restrict__ stats) {
    __shared__ __align__(16) short Albuf[128 * 32];   // [o][k] bf16, swizzled
    __shared__ __align__(16) short Blbuf[128 * 32];   // [p][k] bf16, swizzled
    __shared__ float redbuf[16];

    const int b  = blockIdx.z;
    const int o0 = blockIdx.y * 128;
    const int p0 = blockIdx.x * 128;
    const int t  = threadIdx.x;
    const int w  = t >> 6;          // wave 0..7
    const int l  = t & 63;
    const int wo = (w >> 1) * 32;   // wave o-offset (0/32/64/96)
    const int wp = (w & 1) * 64;    // wave p-offset (0/64)

    const float* fb = feat + (size_t)b * Cq * HWq;

    f32x4 acc[2][4];
    #pragma unroll
    for (int i = 0; i < 2; ++i)
        #pragma unroll
        for (int j = 0; j < 4; ++j)
            acc[i][j] = (f32x4){0.f, 0.f, 0.f, 0.f};

    // A staging: thread t -> o = t>>2 (0..127), ku = t&3 (16B unit)
    const int oA  = t >> 2;
    const int kuA = t & 3;
    const float* aptr = convw + (size_t)(o0 + oA) * Cq + kuA * 8;

    // B staging: thread t -> p = t&127, kg = t>>7 (8 k-rows each)
    const int pB  = t & 127;
    const int kgB = t >> 7;         // 0..3
    int pgB = p0 + pB;
    if (pgB > HWq - 1) pgB = HWq - 1;

    const int fr_g = l >> 4;
    const int fr_r = l & 15;

    float4 ra0, ra1;
    float  rb[8];

    auto LOADG = [&](int k0) {
        ra0 = *(const float4*)(aptr + k0);
        ra1 = *(const float4*)(aptr + k0 + 4);
        const float* fk = fb + (size_t)(k0 + kgB * 8) * HWq + pgB;
        #pragma unroll
        for (int jj = 0; jj < 8; ++jj)
            rb[jj] = fk[(size_t)jj * HWq];
    };

    LOADG(0);

    for (int k0 = 0; k0 < Cq; k0 += 32) {
        if (k0) __syncthreads();               // LDS reads of prev step done

        // ---- LDS write from regs (f32 -> bf16)
        {
            short8v s;
            s[0]=f2bf(ra0.x); s[1]=f2bf(ra0.y); s[2]=f2bf(ra0.z); s[3]=f2bf(ra0.w);
            s[4]=f2bf(ra1.x); s[5]=f2bf(ra1.y); s[6]=f2bf(ra1.z); s[7]=f2bf(ra1.w);
            *(short8v*)((char*)Albuf + oA * 64 + swz(oA, kuA) * 16) = s;
            short8v sb;
            #pragma unroll
            for (int jj = 0; jj < 8; ++jj) sb[jj] = f2bf(rb[jj]);
            *(short8v*)((char*)Blbuf + pB * 64 + swz(pB, kgB) * 16) = sb;
        }
        __syncthreads();

        if (k0 < Cq - 32) LOADG(k0 + 32);      // prefetch next chunk (hides under MFMA)

        short8v af[2], bfv[4];
        #pragma unroll
        for (int i = 0; i < 2; ++i) {
            int row = wo + i * 16 + fr_r;
            af[i] = *(const short8v*)((const char*)Albuf + row * 64 + swz(row, fr_g) * 16);
        }
        #pragma unroll
        for (int j = 0; j < 4; ++j) {
            int row = wp + j * 16 + fr_r;
            bfv[j] = *(const short8v*)((const char*)Blbuf + row * 64 + swz(row, fr_g) * 16);
        }
        #pragma unroll
        for (int i = 0; i < 2; ++i)
            #pragma unroll
            for (int j = 0; j < 4; ++j)
                acc[i][j] = __builtin_amdgcn_mfma_f32_16x16x32_bf16(af[i], bfv[j], acc[i][j], 0, 0, 0);
    }

    // ---- epilogue: bf16 y store + f32 stats
    float lsum = 0.f, lsq = 0.f;
    #pragma unroll
    for (int i = 0; i < 2; ++i) {
        const int obase = o0 + wo + i * 16 + (l >> 4) * 4;
        #pragma unroll
        for (int j = 0; j < 4; ++j) {
            const int p = p0 + wp + j * 16 + (l & 15);
            if (p < HWq) {
                #pragma unroll
                for (int r = 0; r < 4; ++r) {
                    float v = acc[i][j][r];
                    y[((size_t)(b * Oq + obase + r)) * HWq + p] = (unsigned short)f2bf(v);
                    lsum += v;
                    lsq  += v * v;
                }
            }
        }
    }
    #pragma unroll
    for (int m = 1; m < 64; m <<= 1) {
        lsum += __shfl_xor(lsum, m);
        lsq  += __shfl_xor(lsq, m);
    }
    if (l == 0) { redbuf[w] = lsum; redbuf[8 + w] = lsq; }
    __syncthreads();
    if (t == 0) {
        float s0 = 0.f, s1 = 0.f;
        #pragma unroll
        for (int i = 0; i < 8; ++i) { s0 += redbuf[i]; s1 += redbuf[8 + i]; }
        atomicAdd(&stats[b], s0);
        atomicAdd(&stats[8 + b], s1);
    }
}

// ---------------------------------------------------------------------------
// Kernel 2: per-(b,c) plane, 8 waves (512 threads). Each wave owns rows
// wave+8i. Row prefix along x in LDS; pooling = per-box row-range sums,
// 8 lanes/box. (R13 version, unchanged.)
// ---------------------------------------------------------------------------
__global__ __launch_bounds__(512) void integral_pool(const unsigned short* __restrict__ y,
                                                     const float* __restrict__ boxes,
                                                     const float* __restrict__ stats,
                                                     const float* __restrict__ gnw,
                                                     const float* __restrict__ gnb,
                                                     float* __restrict__ pooled) {
    __shared__ float Sl[10000];          // row-prefix values

    const int plane = blockIdx.x;        // b*256 + c
    const int b = plane >> 8;
    const int c = plane & 255;
    const int wave = threadIdx.x >> 6;   // 0..7
    const int lane = threadIdx.x & 63;

    const float invM = 1.f / 2560000.f;
    const float mu   = stats[b] * invM;
    const float msq  = stats[8 + b] * invM;
    const float rs   = rsqrtf(msq - mu * mu + 1e-5f);
    const float scale = gnw[c] * rs;
    const float shift = gnb[c] - mu * scale;

    const unsigned short* yp = y + (size_t)plane * HWq;

    // row prefix: wave owns rows wave+8i; 2-row ILP unroll (7 iterations).
    for (int i = 0; i < 13; i += 2) {
        const int r0 = wave + 8 * i;
        const int r1 = r0 + 8;
        const bool has0 = r0 < 100;
        const bool has1 = r1 < 100;
        float a0 = 0.f, b0 = 0.f, a1 = 0.f, b1 = 0.f;
        if (lane < 50) {
            if (has0) {
                ushort2 u0 = *(const ushort2*)(yp + r0 * 100 + 2 * lane);
                float v0 = bf2f(u0.x) * scale + shift;
                float v1 = bf2f(u0.y) * scale + shift;
                a0 = v0 / (1.f + __expf(-v0));
                b0 = v1 / (1.f + __expf(-v1));
            }
            if (has1) {
                ushort2 u1 = *(const ushort2*)(yp + r1 * 100 + 2 * lane);
                float w0 = bf2f(u1.x) * scale + shift;
                float w1 = bf2f(u1.y) * scale + shift;
                a1 = w0 / (1.f + __expf(-w0));
                b1 = w1 / (1.f + __expf(-w1));
            }
        }
        float p0 = a0 + b0;
        float p1 = a1 + b1;
        #pragma unroll
        for (int m = 1; m < 64; m <<= 1) {
            float t0 = __shfl_up(p0, m);
            float t1 = __shfl_up(p1, m);
            if (lane >= m) { p0 += t0; p1 += t1; }
        }
        if (lane < 50) {
            if (has0) {
                float2 o0 = {p0 - b0, p0};            // inclusive prefix at x=2l, 2l+1
                *(float2*)(&Sl[r0 * 100 + 2 * lane]) = o0;
            }
            if (has1) {
                float2 o1 = {p1 - b1, p1};
                *(float2*)(&Sl[r1 * 100 + 2 * lane]) = o1;
            }
        }
    }
    __syncthreads();

    // pooling: 8 lanes per box; lane j sums rows iy1+j, step 8
    {
        const int grp = lane >> 3;           // 0..7
        const int j   = lane & 7;
        const int n   = wave * 8 + grp;      // 0..63
        const float4 bx = *(const float4*)(boxes + ((size_t)b * 64 + n) * 4);

        float x1f = fminf(bx.x, bx.z) * 100.f;
        float x2f = fmaxf(bx.x, bx.z) * 100.f;
        float y1f = fminf(bx.y, bx.w) * 100.f;
        float y2f = fmaxf(bx.y, bx.w) * 100.f;
        x1f = fminf(fmaxf(floorf(fminf(fmaxf(x1f, 0.f), 100.f)), 0.f), 100.f);
        x2f = fminf(fmaxf(ceilf (fminf(fmaxf(x2f, 0.f), 100.f)), 0.f), 100.f);
        y1f = fminf(fmaxf(floorf(fminf(fmaxf(y1f, 0.f), 100.f)), 0.f), 100.f);
        y2f = fminf(fmaxf(ceilf (fminf(fmaxf(y2f, 0.f), 100.f)), 0.f), 100.f);
        const int ix1 = (int)x1f, ix2 = (int)x2f;
        const int iy1 = (int)y1f, iy2 = (int)y2f;
        const int cnt = (ix2 - ix1) * (iy2 - iy1);

        float v = 0.f;
        if (cnt > 0) {
            const int colR = ix2 - 1;
            const int colL = ix1 - 1;
            for (int h = iy1 + j; h < iy2; h += 8) {
                float s = Sl[h * 100 + colR];
                if (colL >= 0) s -= Sl[h * 100 + colL];
                v += s;
            }
        }
        v += __shfl_xor(v, 1);
        v += __shfl_xor(v, 2);
        v += __shfl_xor(v, 4);
        if (j == 0)
            pooled[((size_t)b * 64 + n) * Cq + c] = (cnt > 0) ? v / (float)cnt : 0.f;
    }
}

// ---------------------------------------------------------------------------
// Kernel 3: MLP (256->128 SiLU ->64) + L2 normalize. One block per (b,n).
// 4-way ILP accumulators break the dependent-FMA chain. (R12 version.)
// ---------------------------------------------------------------------------
__global__ __launch_bounds__(128) void mlp_kernel(const float* __restrict__ pooled,
                                                  const float* __restrict__ w1,
                                                  const float* __restrict__ b1,
                                                  const float* __restrict__ w2,
                                                  const float* __restrict__ b2,
                                                  float* __restrict__ emb,
                                                  float* __restrict__ raw) {
    __shared__ float ps[256];
    __shared__ float hs[128];
    const int bn = blockIdx.x;
    const int t  = threadIdx.x;

    ps[t]       = pooled[(size_t)bn * 256 + t];
    ps[t + 128] = pooled[(size_t)bn * 256 + t + 128];
    __syncthreads();

    float a0 = 0.f, a1 = 0.f, a2 = 0.f, a3 = 0.f;
    #pragma unroll 4
    for (int c = 0; c < 256; c += 4) {
        a0 += ps[c]     * w1[c * 128 + t];
        a1 += ps[c + 1] * w1[(c + 1) * 128 + t];
        a2 += ps[c + 2] * w1[(c + 2) * 128 + t];
        a3 += ps[c + 3] * w1[(c + 3) * 128 + t];
    }
    float a = b1[t] + ((a0 + a1) + (a2 + a3));
    hs[t] = a / (1.f + __expf(-a));
    __syncthreads();

    if (t < 64) {
        float r0 = 0.f, r1 = 0.f, r2 = 0.f, r3 = 0.f;
        #pragma unroll 4
        for (int h = 0; h < 128; h += 4) {
            r0 += hs[h]     * w2[h * 64 + t];
            r1 += hs[h + 1] * w2[(h + 1) * 64 + t];
            r2 += hs[h + 2] * w2[(h + 2) * 64 + t];
            r3 += hs[h + 3] * w2[(h + 3) * 64 + t];
        }
        float r = b2[t] + ((r0 + r1) + (r2 + r3));
        raw[(size_t)bn * 64 + t] = r;
        float s = r * r;
        #pragma unroll
        for (int m = 1; m < 64; m <<= 1) s += __shfl_xor(s, m);
        float nrm = fmaxf(sqrtf(s), 1e-6f);
        emb[(size_t)bn * 64 + t] = r / nrm;
    }
}

// ---------------------------------------------------------------------------
extern "C" void kernel_launch(void* const* d_in, const int* in_sizes, int n_in,
                              void* d_out, int out_size, void* d_ws, size_t ws_size,
                              hipStream_t stream) {
    const float* feat  = (const float*)d_in[0];
    const float* boxes = (const float*)d_in[1];
    const float* convw = (const float*)d_in[2];
    const float* gnw   = (const float*)d_in[3];
    const float* gnb   = (const float*)d_in[4];
    const float* w1    = (const float*)d_in[5];
    const float* b1    = (const float*)d_in[6];
    const float* w2    = (const float*)d_in[7];
    const float* b2    = (const float*)d_in[8];

    float* out    = (float*)d_out;
    float* emb    = out;             // [8,64,64]   = 32768
    float* raw    = out + 32768;     // [8,64,64]   = 32768
    float* pooled = out + 65536;     // [8,64,256]  = 131072

    unsigned short* y = (unsigned short*)d_ws;                     // 8*256*10000 bf16
    float* stats = (float*)((char*)d_ws + (size_t)8 * 256 * 10000 * 2);

    hipMemsetAsync(stats, 0, 16 * sizeof(float), stream);

    dim3 g1((HWq + 127) / 128, 2, 8);   // 79 x 2 x 8 = 1264 blocks, 512 thr
    conv_mfma<<<g1, 512, 0, stream>>>(feat, convw, y, stats);

    integral_pool<<<2048, 512, 0, stream>>>(y, boxes, stats, gnw, gnb, pooled);

    mlp_kernel<<<512, 128, 0, stream>>>(pooled, w1, b1, w2, b2, emb, raw);
}

// Round 17
// 207.294 us; speedup vs baseline: 1.1723x; 1.0260x over previous
//
#include <hip/hip_runtime.h>
#include <hip/hip_bf16.h>
#include <math.h>

#define HWq 10000
#define Cq 256   // in channels (K)
#define Oq 256   // out channels (M)

typedef __attribute__((ext_vector_type(8))) short short8v;           // 8 bf16
typedef __attribute__((ext_vector_type(4))) float f32x4;

__device__ __forceinline__ short f2bf(float f) {
    __hip_bfloat16 h = __float2bfloat16(f);      // RNE; pairs fuse to v_cvt_pk_bf16_f32
    return *reinterpret_cast<short*>(&h);
}
__device__ __forceinline__ float bf2f(unsigned short u) {
    return __uint_as_float((unsigned)u << 16);
}

// XOR swizzle of 16B units within a 64B k-row
__device__ __forceinline__ int swz(int row, int g) {
    return g ^ (row & 3) ^ ((row >> 2) & 1);
}

// ---------------------------------------------------------------------------
// Kernel 1: 1x1 conv as bf16 MFMA GEMM, y stored as bf16.
// Block tile 128o x 128p, BK=32, EIGHT waves (4o x 2p, wave tile 32x64,
// acc 2x4 = 32 regs, ~50 VGPR) + TRUE LDS double-buffer (33 KB):
// one barrier per K-step, loads issued a full step ahead.
// R11 dbuf failed at 4 waves/108 VGPR (occupancy collapse); this is the
// dbuf x high-occupancy cell: LDS-limited 4 blocks/CU x 8 waves = 100%.
// Accumulates per-batch sum/sumsq (f32) into stats[0..7] / stats[8..15].
// ---------------------------------------------------------------------------
__global__ __launch_bounds__(512) void conv_mfma(const float* __restrict__ feat,
                                                 const float* __restrict__ convw,
                                                 unsigned short* __restrict__ y,
                                                 float* __restrict__ stats) {
    __shared__ __align__(16) short Al[2][128 * 32];   // [o][k] bf16, swizzled
    __shared__ __align__(16) short Bl[2][128 * 32];   // [p][k] bf16, swizzled
    __shared__ float redbuf[16];

    const int b  = blockIdx.z;
    const int o0 = blockIdx.y * 128;
    const int p0 = blockIdx.x * 128;
    const int t  = threadIdx.x;
    const int w  = t >> 6;          // wave 0..7
    const int l  = t & 63;
    const int wo = (w >> 1) * 32;   // wave o-offset (0/32/64/96)
    const int wp = (w & 1) * 64;    // wave p-offset (0/64)

    const float* fb = feat + (size_t)b * Cq * HWq;

    f32x4 acc[2][4];
    #pragma unroll
    for (int i = 0; i < 2; ++i)
        #pragma unroll
        for (int j = 0; j < 4; ++j)
            acc[i][j] = (f32x4){0.f, 0.f, 0.f, 0.f};

    // A staging: thread t -> o = t>>2 (0..127), ku = t&3 (16B unit)
    const int oA  = t >> 2;
    const int kuA = t & 3;
    const float* aptr = convw + (size_t)(o0 + oA) * Cq + kuA * 8;

    // B staging: thread t -> p = t&127, kg = t>>7 (8 k-rows each)
    const int pB  = t & 127;
    const int kgB = t >> 7;         // 0..3
    int pgB = p0 + pB;
    if (pgB > HWq - 1) pgB = HWq - 1;

    const int fr_g = l >> 4;
    const int fr_r = l & 15;

    float4 ra0, ra1;
    float  rb[8];

    auto LOADG = [&](int k0) {
        ra0 = *(const float4*)(aptr + k0);
        ra1 = *(const float4*)(aptr + k0 + 4);
        const float* fk = fb + (size_t)(k0 + kgB * 8) * HWq + pgB;
        #pragma unroll
        for (int jj = 0; jj < 8; ++jj)
            rb[jj] = fk[(size_t)jj * HWq];
    };

    auto WRITE = [&](int bi) {
        short8v s;
        s[0]=f2bf(ra0.x); s[1]=f2bf(ra0.y); s[2]=f2bf(ra0.z); s[3]=f2bf(ra0.w);
        s[4]=f2bf(ra1.x); s[5]=f2bf(ra1.y); s[6]=f2bf(ra1.z); s[7]=f2bf(ra1.w);
        *(short8v*)((char*)Al[bi] + oA * 64 + swz(oA, kuA) * 16) = s;
        short8v sb;
        #pragma unroll
        for (int jj = 0; jj < 8; ++jj) sb[jj] = f2bf(rb[jj]);
        *(short8v*)((char*)Bl[bi] + pB * 64 + swz(pB, kgB) * 16) = sb;
    };

    LOADG(0);
    WRITE(0);
    LOADG(32);                 // tile 1 into regs (consumed next step)
    __syncthreads();           // buf0 ready

    int cur = 0;
    for (int k0 = 0; k0 < Cq; k0 += 32) {
        // fragment reads from current buffer (MFMA waits only on these)
        short8v af[2], bfv[4];
        #pragma unroll
        for (int i = 0; i < 2; ++i) {
            int row = wo + i * 16 + fr_r;
            af[i] = *(const short8v*)((const char*)Al[cur] + row * 64 + swz(row, fr_g) * 16);
        }
        #pragma unroll
        for (int j = 0; j < 4; ++j) {
            int row = wp + j * 16 + fr_r;
            bfv[j] = *(const short8v*)((const char*)Bl[cur] + row * 64 + swz(row, fr_g) * 16);
        }
        // stage next tile into other buffer; issue loads for tile k0+64
        if (k0 + 32 < Cq) {
            WRITE(cur ^ 1);
            if (k0 + 64 < Cq) LOADG(k0 + 64);
        }
        #pragma unroll
        for (int i = 0; i < 2; ++i)
            #pragma unroll
            for (int j = 0; j < 4; ++j)
                acc[i][j] = __builtin_amdgcn_mfma_f32_16x16x32_bf16(af[i], bfv[j], acc[i][j], 0, 0, 0);
        __syncthreads();       // one barrier per K-step
        cur ^= 1;
    }

    // ---- epilogue: bf16 y store + f32 stats
    float lsum = 0.f, lsq = 0.f;
    #pragma unroll
    for (int i = 0; i < 2; ++i) {
        const int obase = o0 + wo + i * 16 + (l >> 4) * 4;
        #pragma unroll
        for (int j = 0; j < 4; ++j) {
            const int p = p0 + wp + j * 16 + (l & 15);
            if (p < HWq) {
                #pragma unroll
                for (int r = 0; r < 4; ++r) {
                    float v = acc[i][j][r];
                    y[((size_t)(b * Oq + obase + r)) * HWq + p] = (unsigned short)f2bf(v);
                    lsum += v;
                    lsq  += v * v;
                }
            }
        }
    }
    #pragma unroll
    for (int m = 1; m < 64; m <<= 1) {
        lsum += __shfl_xor(lsum, m);
        lsq  += __shfl_xor(lsq, m);
    }
    if (l == 0) { redbuf[w] = lsum; redbuf[8 + w] = lsq; }
    __syncthreads();
    if (t == 0) {
        float s0 = 0.f, s1 = 0.f;
        #pragma unroll
        for (int i = 0; i < 8; ++i) { s0 += redbuf[i]; s1 += redbuf[8 + i]; }
        atomicAdd(&stats[b], s0);
        atomicAdd(&stats[8 + b], s1);
    }
}

// ---------------------------------------------------------------------------
// Kernel 2: per-(b,c) plane, 8 waves (512 threads). Each wave owns rows
// wave+8i. Row prefix along x in LDS; pooling = per-box row-range sums,
// 8 lanes/box. (R13 version, unchanged.)
// ---------------------------------------------------------------------------
__global__ __launch_bounds__(512) void integral_pool(const unsigned short* __restrict__ y,
                                                     const float* __restrict__ boxes,
                                                     const float* __restrict__ stats,
                                                     const float* __restrict__ gnw,
                                                     const float* __restrict__ gnb,
                                                     float* __restrict__ pooled) {
    __shared__ float Sl[10000];          // row-prefix values

    const int plane = blockIdx.x;        // b*256 + c
    const int b = plane >> 8;
    const int c = plane & 255;
    const int wave = threadIdx.x >> 6;   // 0..7
    const int lane = threadIdx.x & 63;

    const float invM = 1.f / 2560000.f;
    const float mu   = stats[b] * invM;
    const float msq  = stats[8 + b] * invM;
    const float rs   = rsqrtf(msq - mu * mu + 1e-5f);
    const float scale = gnw[c] * rs;
    const float shift = gnb[c] - mu * scale;

    const unsigned short* yp = y + (size_t)plane * HWq;

    // row prefix: wave owns rows wave+8i; 2-row ILP unroll (7 iterations).
    for (int i = 0; i < 13; i += 2) {
        const int r0 = wave + 8 * i;
        const int r1 = r0 + 8;
        const bool has0 = r0 < 100;
        const bool has1 = r1 < 100;
        float a0 = 0.f, b0 = 0.f, a1 = 0.f, b1 = 0.f;
        if (lane < 50) {
            if (has0) {
                ushort2 u0 = *(const ushort2*)(yp + r0 * 100 + 2 * lane);
                float v0 = bf2f(u0.x) * scale + shift;
                float v1 = bf2f(u0.y) * scale + shift;
                a0 = v0 / (1.f + __expf(-v0));
                b0 = v1 / (1.f + __expf(-v1));
            }
            if (has1) {
                ushort2 u1 = *(const ushort2*)(yp + r1 * 100 + 2 * lane);
                float w0 = bf2f(u1.x) * scale + shift;
                float w1 = bf2f(u1.y) * scale + shift;
                a1 = w0 / (1.f + __expf(-w0));
                b1 = w1 / (1.f + __expf(-w1));
            }
        }
        float p0 = a0 + b0;
        float p1 = a1 + b1;
        #pragma unroll
        for (int m = 1; m < 64; m <<= 1) {
            float t0 = __shfl_up(p0, m);
            float t1 = __shfl_up(p1, m);
            if (lane >= m) { p0 += t0; p1 += t1; }
        }
        if (lane < 50) {
            if (has0) {
                float2 o0 = {p0 - b0, p0};            // inclusive prefix at x=2l, 2l+1
                *(float2*)(&Sl[r0 * 100 + 2 * lane]) = o0;
            }
            if (has1) {
                float2 o1 = {p1 - b1, p1};
                *(float2*)(&Sl[r1 * 100 + 2 * lane]) = o1;
            }
        }
    }
    __syncthreads();

    // pooling: 8 lanes per box; lane j sums rows iy1+j, step 8
    {
        const int grp = lane >> 3;           // 0..7
        const int j   = lane & 7;
        const int n   = wave * 8 + grp;      // 0..63
        const float4 bx = *(const float4*)(boxes + ((size_t)b * 64 + n) * 4);

        float x1f = fminf(bx.x, bx.z) * 100.f;
        float x2f = fmaxf(bx.x, bx.z) * 100.f;
        float y1f = fminf(bx.y, bx.w) * 100.f;
        float y2f = fmaxf(bx.y, bx.w) * 100.f;
        x1f = fminf(fmaxf(floorf(fminf(fmaxf(x1f, 0.f), 100.f)), 0.f), 100.f);
        x2f = fminf(fmaxf(ceilf (fminf(fmaxf(x2f, 0.f), 100.f)), 0.f), 100.f);
        y1f = fminf(fmaxf(floorf(fminf(fmaxf(y1f, 0.f), 100.f)), 0.f), 100.f);
        y2f = fminf(fmaxf(ceilf (fminf(fmaxf(y2f, 0.f), 100.f)), 0.f), 100.f);
        const int ix1 = (int)x1f, ix2 = (int)x2f;
        const int iy1 = (int)y1f, iy2 = (int)y2f;
        const int cnt = (ix2 - ix1) * (iy2 - iy1);

        float v = 0.f;
        if (cnt > 0) {
            const int colR = ix2 - 1;
            const int colL = ix1 - 1;
            for (int h = iy1 + j; h < iy2; h += 8) {
                float s = Sl[h * 100 + colR];
                if (colL >= 0) s -= Sl[h * 100 + colL];
                v += s;
            }
        }
        v += __shfl_xor(v, 1);
        v += __shfl_xor(v, 2);
        v += __shfl_xor(v, 4);
        if (j == 0)
            pooled[((size_t)b * 64 + n) * Cq + c] = (cnt > 0) ? v / (float)cnt : 0.f;
    }
}

// ---------------------------------------------------------------------------
// Kernel 3: MLP (256->128 SiLU ->64) + L2 normalize. One block per (b,n).
// 4-way ILP accumulators break the dependent-FMA chain. (R12 version.)
// ---------------------------------------------------------------------------
__global__ __launch_bounds__(128) void mlp_kernel(const float* __restrict__ pooled,
                                                  const float* __restrict__ w1,
                                                  const float* __restrict__ b1,
                                                  const float* __restrict__ w2,
                                                  const float* __restrict__ b2,
                                                  float* __restrict__ emb,
                                                  float* __restrict__ raw) {
    __shared__ float ps[256];
    __shared__ float hs[128];
    const int bn = blockIdx.x;
    const int t  = threadIdx.x;

    ps[t]       = pooled[(size_t)bn * 256 + t];
    ps[t + 128] = pooled[(size_t)bn * 256 + t + 128];
    __syncthreads();

    float a0 = 0.f, a1 = 0.f, a2 = 0.f, a3 = 0.f;
    #pragma unroll 4
    for (int c = 0; c < 256; c += 4) {
        a0 += ps[c]     * w1[c * 128 + t];
        a1 += ps[c + 1] * w1[(c + 1) * 128 + t];
        a2 += ps[c + 2] * w1[(c + 2) * 128 + t];
        a3 += ps[c + 3] * w1[(c + 3) * 128 + t];
    }
    float a = b1[t] + ((a0 + a1) + (a2 + a3));
    hs[t] = a / (1.f + __expf(-a));
    __syncthreads();

    if (t < 64) {
        float r0 = 0.f, r1 = 0.f, r2 = 0.f, r3 = 0.f;
        #pragma unroll 4
        for (int h = 0; h < 128; h += 4) {
            r0 += hs[h]     * w2[h * 64 + t];
            r1 += hs[h + 1] * w2[(h + 1) * 64 + t];
            r2 += hs[h + 2] * w2[(h + 2) * 64 + t];
            r3 += hs[h + 3] * w2[(h + 3) * 64 + t];
        }
        float r = b2[t] + ((r0 + r1) + (r2 + r3));
        raw[(size_t)bn * 64 + t] = r;
        float s = r * r;
        #pragma unroll
        for (int m = 1; m < 64; m <<= 1) s += __shfl_xor(s, m);
        float nrm = fmaxf(sqrtf(s), 1e-6f);
        emb[(size_t)bn * 64 + t] = r / nrm;
    }
}

// ---------------------------------------------------------------------------
extern "C" void kernel_launch(void* const* d_in, const int* in_sizes, int n_in,
                              void* d_out, int out_size, void* d_ws, size_t ws_size,
                              hipStream_t stream) {
    const float* feat  = (const float*)d_in[0];
    const float* boxes = (const float*)d_in[1];
    const float* convw = (const float*)d_in[2];
    const float* gnw   = (const float*)d_in[3];
    const float* gnb   = (const float*)d_in[4];
    const float* w1    = (const float*)d_in[5];
    const float* b1    = (const float*)d_in[6];
    const float* w2    = (const float*)d_in[7];
    const float* b2    = (const float*)d_in[8];

    float* out    = (float*)d_out;
    float* emb    = out;             // [8,64,64]   = 32768
    float* raw    = out + 32768;     // [8,64,64]   = 32768
    float* pooled = out + 65536;     // [8,64,256]  = 131072

    unsigned short* y = (unsigned short*)d_ws;                     // 8*256*10000 bf16
    float* stats = (float*)((char*)d_ws + (size_t)8 * 256 * 10000 * 2);

    hipMemsetAsync(stats, 0, 16 * sizeof(float), stream);

    dim3 g1((HWq + 127) / 128, 2, 8);   // 79 x 2 x 8 = 1264 blocks, 512 thr
    conv_mfma<<<g1, 512, 0, stream>>>(feat, convw, y, stats);

    integral_pool<<<2048, 512, 0, stream>>>(y, boxes, stats, gnw, gnb, pooled);

    mlp_kernel<<<512, 128, 0, stream>>>(pooled, w1, b1, w2, b2, emb, raw);
}